// Round 12
// baseline (97.767 us; speedup 1.0000x reference)
//
#include <hip/hip_runtime.h>

#define M_ROWS 1024
#define DIM 512
#define NB 1024              // row bytes = DIM*2
#define N_TOT 7168           // M + 2*M*C
#define TEXT_OFF 1024
#define SHUF_OFF 4096
#define INV_T (1.0f/0.07f)
#define MARGIN_V 0.2f
#define TILES 56             // N_TOT / 128
#define NBLK 1596            // 56*57/2 upper-triangular 128^2 tiles
#define SLOT 768             // floats per slot: [2 sides][3 vals][128 rows]

typedef __attribute__((ext_vector_type(8))) short bf16x8;
typedef __attribute__((ext_vector_type(4))) float f32x4;

typedef const __attribute__((address_space(1))) unsigned int gas_uint;
typedef __attribute__((address_space(3))) unsigned int las_uint;

__device__ __forceinline__ void gload16(const void* g, void* l) {
  __builtin_amdgcn_global_load_lds((gas_uint*)g, (las_uint*)l, 16, 0, 0);
}

__device__ __forceinline__ ushort f2bf(float f) {
  unsigned u = __float_as_uint(f);
  u += 0x7fffu + ((u >> 16) & 1u);   // RTNE
  return (ushort)(u >> 16);
}

// DPP 16-lane row sum on the VALU pipe; total lands in lane 15 of each row.
__device__ __forceinline__ float dpp_sum16(float x) {
  float s = x;
  s += __int_as_float(__builtin_amdgcn_update_dpp(0, __float_as_int(s), 0x111, 0xF, 0xF, true));
  s += __int_as_float(__builtin_amdgcn_update_dpp(0, __float_as_int(s), 0x112, 0xF, 0xF, true));
  s += __int_as_float(__builtin_amdgcn_update_dpp(0, __float_as_int(s), 0x114, 0xF, 0xF, true));
  s += __int_as_float(__builtin_amdgcn_update_dpp(0, __float_as_int(s), 0x118, 0xF, 0xF, true));
  return s;
}

// ------- Kernel 1: normalize + cast bf16 + build ids -------
__global__ __launch_bounds__(256) void k_normalize(
    const float* __restrict__ motion, const float* __restrict__ text,
    const float* __restrict__ shuf, const int* __restrict__ mids,
    ushort* __restrict__ emb, int* __restrict__ ids) {
  int wave = threadIdx.x >> 6;
  int lane = threadIdx.x & 63;
  int row = blockIdx.x * 4 + wave;
  if (row >= N_TOT) return;
  const float* src;
  int id;
  if (row < TEXT_OFF) { src = motion + (size_t)row * DIM; id = mids[row]; }
  else if (row < SHUF_OFF) { int r = row - TEXT_OFF; src = text + (size_t)r * DIM; id = mids[r / 3]; }
  else { int r = row - SHUF_OFF; src = shuf + (size_t)r * DIM; id = mids[r / 3] + 100000; }

  float4 a = ((const float4*)src)[lane * 2];
  float4 b = ((const float4*)src)[lane * 2 + 1];
  float v0 = a.x + 1e-8f, v1 = a.y + 1e-8f, v2 = a.z + 1e-8f, v3 = a.w + 1e-8f;
  float v4 = b.x + 1e-8f, v5 = b.y + 1e-8f, v6 = b.z + 1e-8f, v7 = b.w + 1e-8f;
  float ss = v0*v0 + v1*v1 + v2*v2 + v3*v3 + v4*v4 + v5*v5 + v6*v6 + v7*v7;
  #pragma unroll
  for (int m = 1; m < 64; m <<= 1) ss += __shfl_xor(ss, m);
  float inv = 1.0f / fmaxf(sqrtf(ss), 1e-12f);

  uint w0 = (uint)f2bf(v0 * inv) | ((uint)f2bf(v1 * inv) << 16);
  uint w1 = (uint)f2bf(v2 * inv) | ((uint)f2bf(v3 * inv) << 16);
  uint w2 = (uint)f2bf(v4 * inv) | ((uint)f2bf(v5 * inv) << 16);
  uint w3 = (uint)f2bf(v6 * inv) | ((uint)f2bf(v7 * inv) << 16);
  uint4 pk; pk.x = w0; pk.y = w1; pk.z = w2; pk.w = w3;
  *((uint4*)(emb + (size_t)row * DIM + lane * 8)) = pk;
  if (lane == 0) ids[row] = id;
}

// -------- Kernel 2: symmetric fused A*A^T, 128^2 tiles, 4 waves --------
// WAVE-INDEPENDENT K-loop: each wave stages its own 64-row A and B operand
// chunks into a PRIVATE 16 KB LDS region (2 buffers). Only the issuing wave
// reads its region -> sync is its own vmcnt(0), a full step after issue.
// ZERO s_barrier in the K-loop: no convoy, waves self-pace; 8 free-running
// waves/CU hide each other's memory jitter. DPP epilogue; slot partials.
__global__ __launch_bounds__(256, 2) void k_gemm_loss(
    const ushort* __restrict__ emb, const int* __restrict__ ids,
    float* __restrict__ part) {
  __shared__ ushort Aw[4][2][2048];   // [wave][buf][64 rows x 32 bf16] = 4 KB
  __shared__ ushort Bw[4][2][2048];   // total 64 KB -> 2 blocks/CU

  // bijective XCD-chunked swizzle: nwg=1596, q=199, r=4
  int orig = blockIdx.x;
  int xcd = orig & 7;
  int idx = orig >> 3;
  int bid = (xcd < 4 ? xcd * 200 : 800 + (xcd - 4) * 199) + idx;

  // triangular tile decode: bid -> (x, y), x <= y
  int x = 0;
  while (bid >= TILES - x) { bid -= TILES - x; x++; }
  int y = x + bid;
  bool diag = (x == y);
  int brow = x * 128, bcol = y * 128;
  int tbid = x * TILES - x * (x - 1) / 2 + (y - x);   // linear triangular id

  int t = threadIdx.x;
  int l = t & 63;
  int w = t >> 6;            // wave 0..3
  int wr = w >> 1;           // wave row 0..1  -> 64 output rows
  int wc = w & 1;            // wave col 0..1  -> 64 output cols
  int fr = l & 15;
  int fg = l >> 4;           // 0..3

  // staging (per wave, private): gload g covers rows [g*16, g*16+16) of the
  // wave's 64-row chunk; lane l -> row g*16 + (l>>2), pre-swizzled col.
  // swizzle invariant: (row>>1)&3 == ((l>>2)>>1)&3 == (l>>3)&3 (g*16 even*8).
  int srow = l >> 2;
  int scol = ((l & 3) ^ ((l >> 3) & 3)) * 16;
  const char* gA = (const char*)emb + (size_t)(brow + wr * 64 + srow) * NB + scol;
  const char* gB = (const char*)emb + (size_t)(bcol + wc * 64 + srow) * NB + scol;

  f32x4 acc[4][4];
  #pragma unroll
  for (int m = 0; m < 4; m++)
    #pragma unroll
    for (int n = 0; n < 4; n++)
      acc[m][n] = (f32x4){0.f, 0.f, 0.f, 0.f};

  // swizzled ds_read col offset (ushorts): phys colgroup = fg ^ ((fr>>1)&3)
  int swz = (fg ^ ((fr >> 1) & 3)) * 8;

#define STAGE(T) do { \
    const int _b = (T) & 1; const int _kb = (T) * 64; \
    _Pragma("unroll") \
    for (int _g = 0; _g < 4; _g++) { \
      gload16(gA + (size_t)_g * 16 * NB + _kb, &Aw[w][_b][_g * 512]); \
      gload16(gB + (size_t)_g * 16 * NB + _kb, &Bw[w][_b][_g * 512]); \
    } \
  } while (0)

  STAGE(0);
  asm volatile("s_waitcnt vmcnt(0)" ::: "memory");   // own 8 loads only

  #pragma unroll
  for (int tt = 0; tt < 16; tt++) {
    if (tt < 15) STAGE(tt + 1);        // issue early: full step to cover latency
    const int _b = tt & 1;
    const ushort* Ab = &Aw[w][_b][fr * 32 + swz];
    const ushort* Bb = &Bw[w][_b][fr * 32 + swz];
    bf16x8 aF[4], bF[4];
    #pragma unroll
    for (int m = 0; m < 4; m++) aF[m] = *(const bf16x8*)(Ab + m * 512);
    #pragma unroll
    for (int n = 0; n < 4; n++) bF[n] = *(const bf16x8*)(Bb + n * 512);
    __builtin_amdgcn_s_setprio(1);
    #pragma unroll
    for (int m = 0; m < 4; m++)
      #pragma unroll
      for (int n = 0; n < 4; n++)
        acc[m][n] = __builtin_amdgcn_mfma_f32_16x16x32_bf16(aF[m], bF[n], acc[m][n], 0, 0, 0);
    __builtin_amdgcn_s_setprio(0);
    if (tt < 15)
      asm volatile("s_waitcnt vmcnt(0)" ::: "memory");   // own next-buf loads
  }
#undef STAGE

  // ---- reuse LDS after the K-loop ----
  __syncthreads();                      // all waves done with their regions
  float* rpd = (float*)&Aw[0][0][0];    // [4 waves][64 rows] x 3 (3 KB, in Aw[0])
  float* rpp = rpd + 256;
  float* rpm = rpp + 256;
  float* cps = (float*)&Bw[0][0][0];    // [4 waves][4 n][16 cl][3] (3 KB, Bw[0])
  int* ridL = (int*)&Aw[1][0][0];       // 1 KB, in Aw[1]
  int* cidL = ridL + 128;
  if (t < 128) ridL[t] = ids[brow + t];
  else if (t < 256) cidL[t - 128] = ids[bcol + (t - 128)];
  __syncthreads();

  float* ps = part + (size_t)tbid * SLOT;   // [side][3 vals][128]

  // ---- epilogue: per-element masks; DPP row-reduce ----
  int cl = fr;
  int cgrp = fg;
  int cidv[4];
  #pragma unroll
  for (int n = 0; n < 4; n++) cidv[n] = cidL[wc * 64 + n * 16 + cl];
  float cd[4], cp[4], cm[4];
  #pragma unroll
  for (int n = 0; n < 4; n++) { cd[n] = 0.f; cp[n] = 0.f; cm[n] = 0.f; }

  #pragma unroll
  for (int m = 0; m < 4; m++) {
    #pragma unroll
    for (int r = 0; r < 4; r++) {
      int row_l = wr * 64 + m * 16 + cgrp * 4 + r;
      int i = brow + row_l;
      int idi = ridL[row_l];
      float dsum = 0.f, psum = 0.f, msum = 0.f;
      #pragma unroll
      for (int n = 0; n < 4; n++) {
        int col_l = wc * 64 + n * 16 + cl;
        int j = bcol + col_l;
        float sim = acc[m][n][r] * INV_T;
        bool live = (!diag) || (i != j);
        if (live) {
          float e = __expf(sim);
          float hinge = fmaxf(sim + MARGIN_V, 0.f);
          bool same = (idi == cidv[n]);
          float psv = same ? sim : 0.f;
          float msv = same ? 0.f : hinge;
          dsum += e; psum += psv; msum += msv;
          if (!diag) { cd[n] += e; cp[n] += psv; cm[n] += msv; }
        }
      }
      dsum = dpp_sum16(dsum);
      psum = dpp_sum16(psum);
      msum = dpp_sum16(msum);
      if (cl == 15) {
        int o = w * 64 + (row_l & 63);
        rpd[o] = dsum; rpp[o] = psum; rpm[o] = msum;
      }
    }
  }

  if (!diag) {
    // col partials: shfl-combine the 4 fg-groups within the wave
    #pragma unroll
    for (int n = 0; n < 4; n++) {
      float d = cd[n], p = cp[n], mm = cm[n];
      d += __shfl_xor(d, 16); d += __shfl_xor(d, 32);
      p += __shfl_xor(p, 16); p += __shfl_xor(p, 32);
      mm += __shfl_xor(mm, 16); mm += __shfl_xor(mm, 32);
      if (l < 16) {
        int o = ((w * 4 + n) * 16 + cl) * 3;
        cps[o] = d; cps[o + 1] = p; cps[o + 2] = mm;
      }
    }
  }
  __syncthreads();

  // row side: sum the 2 wc-wave slices, coalesced store
  if (t < 128) {
    int b0 = (t >> 6) * 128 + (t & 63);
    float d = rpd[b0] + rpd[b0 + 64];
    float p = rpp[b0] + rpp[b0 + 64];
    float mm = rpm[b0] + rpm[b0 + 64];
    ps[t] = d; ps[128 + t] = p; ps[256 + t] = mm;
  }
  // col side: combine wr=0/wr=1 pairs (w and w+2), store
  if (!diag && wr == 0 && l < 16) {
    #pragma unroll
    for (int n = 0; n < 4; n++) {
      int o0 = ((w * 4 + n) * 16 + cl) * 3;
      int o1 = (((w + 2) * 4 + n) * 16 + cl) * 3;
      int col_l = w * 64 + n * 16 + cl;   // wc == w when wr == 0
      ps[384 + col_l] = cps[o0] + cps[o1];
      ps[384 + 128 + col_l] = cps[o0 + 1] + cps[o1 + 1];
      ps[384 + 256 + col_l] = cps[o0 + 2] + cps[o1 + 2];
    }
  }
}

// ---- Kernel 3: reduce partials + per-row loss + per-block partial sum ----
__global__ __launch_bounds__(256) void k_reduce(
    const float* __restrict__ part, const int* __restrict__ mids,
    float* __restrict__ blockout) {
  __shared__ int hist[256];
  __shared__ float reds[256];
  __shared__ int redc[256];
  int t = threadIdx.x;
  hist[t] = 0;
  __syncthreads();
  for (int i = t; i < M_ROWS; i += 256) atomicAdd(&hist[mids[i]], 1);
  __syncthreads();

  int i = blockIdx.x * 256 + t;            // row 0..7167
  int p = i >> 7;                          // 128-row panel 0..55 (wave-uniform)
  int v = i & 127;
  float d = 0.f, pp = 0.f, mm = 0.f;
  int base = p * TILES - p * (p - 1) / 2;  // tbid(p, p)
  for (int yy = p; yy < TILES; yy++) {     // row-side from tiles (p, yy)
    const float* s = part + (size_t)(base + yy - p) * SLOT;
    d += s[v]; pp += s[128 + v]; mm += s[256 + v];
  }
  for (int xx = 0; xx < p; xx++) {         // col-side from tiles (xx, p)
    int b = xx * TILES - xx * (xx - 1) / 2 + (p - xx);
    const float* s = part + (size_t)b * SLOT + 384;
    d += s[v]; pp += s[128 + v]; mm += s[256 + v];
  }

  int vmid; bool sh = false;
  if (i < TEXT_OFF) vmid = mids[i];
  else if (i < SHUF_OFF) vmid = mids[(i - TEXT_OFF) / 3];
  else { vmid = mids[(i - SHUF_OFF) / 3]; sh = true; }
  int c = hist[vmid];
  int npos = sh ? (3 * c - 1) : (4 * c - 1);
  int nneg = N_TOT - 1 - npos;
  float val = 0.f; int cnt = 0;
  if (npos > 0 && nneg > 0) {
    val = logf(d) - pp / (float)(npos > 1 ? npos : 1) + mm / (float)(nneg > 1 ? nneg : 1);
    cnt = 1;
  }
  reds[t] = val; redc[t] = cnt;
  __syncthreads();
  for (int s2 = 128; s2 > 0; s2 >>= 1) {
    if (t < s2) { reds[t] += reds[t + s2]; redc[t] += redc[t + s2]; }
    __syncthreads();
  }
  if (t == 0) { blockout[blockIdx.x * 2] = reds[0]; blockout[blockIdx.x * 2 + 1] = (float)redc[0]; }
}

// ---------------- Kernel 4: final scalar ----------------
__global__ __launch_bounds__(64) void k_final(
    const float* __restrict__ blockout, float* __restrict__ out) {
  int t = threadIdx.x;
  float s = 0.f, c = 0.f;
  if (t < 28) { s = blockout[t * 2]; c = blockout[t * 2 + 1]; }
  #pragma unroll
  for (int m = 32; m > 0; m >>= 1) { s += __shfl_down(s, m); c += __shfl_down(c, m); }
  if (t == 0) out[0] = (c > 0.f) ? s / c : 0.f;
}

// ---------------- Launch ----------------
extern "C" void kernel_launch(void* const* d_in, const int* in_sizes, int n_in,
                              void* d_out, int out_size, void* d_ws, size_t ws_size,
                              hipStream_t stream) {
  const float* motion = (const float*)d_in[0];
  const float* text   = (const float*)d_in[1];
  const float* shuf   = (const float*)d_in[2];
  const int*   mids   = (const int*)d_in[3];

  char* ws = (char*)d_ws;
  ushort* emb = (ushort*)ws;                                  // 7,340,032 B
  int* ids    = (int*)(ws + 7340032);                         // 28,672 B
  float* blockout = (float*)(ws + 7368704);                   // 28*2 floats
  float* part = (float*)(ws + 7372800);                       // 1596*768*4 = 4,902,912 B

  k_normalize<<<N_TOT / 4, 256, 0, stream>>>(motion, text, shuf, mids, emb, ids);
  k_gemm_loss<<<NBLK, 256, 0, stream>>>(emb, ids, part);
  k_reduce<<<TILES / 2, 256, 0, stream>>>(part, mids, blockout);
  k_final<<<1, 64, 0, stream>>>(blockout, (float*)d_out);
}

// Round 13
// 75.287 us; speedup vs baseline: 1.2986x; 1.2986x over previous
//
#include <hip/hip_runtime.h>

#define M_ROWS 1024
#define DIM 512
#define NB 1024              // row bytes = DIM*2
#define N_TOT 7168           // M + 2*M*C
#define TEXT_OFF 1024
#define SHUF_OFF 4096
#define INV_T (1.0f/0.07f)
#define MARGIN_V 0.2f
#define TILES2 28            // N_TOT / 256
#define NBLK2 406            // 28*29/2 upper-triangular 256^2 tiles
#define SLOT 1536            // floats per slot: [2 sides][3 vals][256 rows]

typedef __attribute__((ext_vector_type(8))) short bf16x8;
typedef __attribute__((ext_vector_type(4))) float f32x4;

typedef const __attribute__((address_space(1))) unsigned int gas_uint;
typedef __attribute__((address_space(3))) unsigned int las_uint;

__device__ __forceinline__ void gload16(const void* g, void* l) {
  __builtin_amdgcn_global_load_lds((gas_uint*)g, (las_uint*)l, 16, 0, 0);
}

__device__ __forceinline__ ushort f2bf(float f) {
  unsigned u = __float_as_uint(f);
  u += 0x7fffu + ((u >> 16) & 1u);   // RTNE
  return (ushort)(u >> 16);
}

// DPP 16-lane row sum on the VALU pipe; total lands in lane 15 of each row.
__device__ __forceinline__ float dpp_sum16(float x) {
  float s = x;
  s += __int_as_float(__builtin_amdgcn_update_dpp(0, __float_as_int(s), 0x111, 0xF, 0xF, true));
  s += __int_as_float(__builtin_amdgcn_update_dpp(0, __float_as_int(s), 0x112, 0xF, 0xF, true));
  s += __int_as_float(__builtin_amdgcn_update_dpp(0, __float_as_int(s), 0x114, 0xF, 0xF, true));
  s += __int_as_float(__builtin_amdgcn_update_dpp(0, __float_as_int(s), 0x118, 0xF, 0xF, true));
  return s;
}

// ------- Kernel 1: normalize + cast bf16 + build ids -------
__global__ __launch_bounds__(256) void k_normalize(
    const float* __restrict__ motion, const float* __restrict__ text,
    const float* __restrict__ shuf, const int* __restrict__ mids,
    ushort* __restrict__ emb, int* __restrict__ ids) {
  int wave = threadIdx.x >> 6;
  int lane = threadIdx.x & 63;
  int row = blockIdx.x * 4 + wave;
  if (row >= N_TOT) return;
  const float* src;
  int id;
  if (row < TEXT_OFF) { src = motion + (size_t)row * DIM; id = mids[row]; }
  else if (row < SHUF_OFF) { int r = row - TEXT_OFF; src = text + (size_t)r * DIM; id = mids[r / 3]; }
  else { int r = row - SHUF_OFF; src = shuf + (size_t)r * DIM; id = mids[r / 3] + 100000; }

  float4 a = ((const float4*)src)[lane * 2];
  float4 b = ((const float4*)src)[lane * 2 + 1];
  float v0 = a.x + 1e-8f, v1 = a.y + 1e-8f, v2 = a.z + 1e-8f, v3 = a.w + 1e-8f;
  float v4 = b.x + 1e-8f, v5 = b.y + 1e-8f, v6 = b.z + 1e-8f, v7 = b.w + 1e-8f;
  float ss = v0*v0 + v1*v1 + v2*v2 + v3*v3 + v4*v4 + v5*v5 + v6*v6 + v7*v7;
  #pragma unroll
  for (int m = 1; m < 64; m <<= 1) ss += __shfl_xor(ss, m);
  float inv = 1.0f / fmaxf(sqrtf(ss), 1e-12f);

  uint w0 = (uint)f2bf(v0 * inv) | ((uint)f2bf(v1 * inv) << 16);
  uint w1 = (uint)f2bf(v2 * inv) | ((uint)f2bf(v3 * inv) << 16);
  uint w2 = (uint)f2bf(v4 * inv) | ((uint)f2bf(v5 * inv) << 16);
  uint w3 = (uint)f2bf(v6 * inv) | ((uint)f2bf(v7 * inv) << 16);
  uint4 pk; pk.x = w0; pk.y = w1; pk.z = w2; pk.w = w3;
  *((uint4*)(emb + (size_t)row * DIM + lane * 8)) = pk;
  if (lane == 0) ids[row] = id;
}

// -------- Kernel 2: symmetric fused A*A^T, 256^2, 8-phase schedule --------
// m201-style: BK=64, 2 K-tiles per iteration (even->dbuf0, odd->dbuf1),
// 8 phases = 2 K-tiles x 4 C-quadrants, each phase {ds-read quadrant regs ||
// stage 1 half-tile -> barrier -> setprio MFMA -> barrier}. Drains (vmcnt(0)
// + barrier) only at phases 3/7 ends. 8-group XOR swizzle for 128B rows.
__global__ __launch_bounds__(512, 1) void k_gemm_loss(
    const ushort* __restrict__ emb, const int* __restrict__ ids,
    float* __restrict__ part) {
  __shared__ ushort Asm[2][2][8192];   // [dbuf=kt&1][half][128 rows x 64 bf16]
  __shared__ ushort Bsm[2][2][8192];   // total 128 KB

  // bijective XCD-chunked swizzle: nwg=406, q=50, r=6
  int orig = blockIdx.x;
  int xcd = orig & 7;
  int idx = orig >> 3;
  int bid = (xcd < 6 ? xcd * 51 : 306 + (xcd - 6) * 50) + idx;

  int x = 0;
  while (bid >= TILES2 - x) { bid -= TILES2 - x; x++; }
  int y = x + bid;
  bool diag = (x == y);
  int brow = x * 256, bcol = y * 256;
  int tbid = x * TILES2 - x * (x - 1) / 2 + (y - x);

  int t = threadIdx.x;
  int l = t & 63;
  int w = t >> 6;            // wave 0..7
  int wr = w >> 2;           // 0..1 -> 128 output rows
  int wc = w & 3;            // 0..3 -> 64 output cols
  int fr = l & 15;
  int fg = l >> 4;           // 0..3

  // staging: wave w stages 8 rows per gload round; lane l -> row w*8+(l>>3),
  // 16B-group pre-swizzled: lg = (l&7) ^ (row&7), row&7 == (l>>3)&7
  int srow = w * 8 + (l >> 3);
  int sgb = ((l & 7) ^ ((l >> 3) & 7)) * 16;
  const char* gAr = (const char*)emb + (size_t)(brow + srow) * NB + sgb;
  const char* gBr = (const char*)emb + (size_t)(bcol + srow) * NB + sgb;

  f32x4 acc[8][4];
  #pragma unroll
  for (int m = 0; m < 8; m++)
    #pragma unroll
    for (int n = 0; n < 4; n++)
      acc[m][n] = (f32x4){0.f, 0.f, 0.f, 0.f};

  // read-side swizzled group offsets (ushorts): phys = (ks*4+fg) ^ (fr&7)
  int sw0 = ((fg) ^ (fr & 7)) * 8;
  int sw1 = ((4 + fg) ^ (fr & 7)) * 8;

#define STAGE_A(H, KT) do { \
    gload16(gAr + (size_t)(H) * 131072 + (KT) * 128,         &Asm[(KT) & 1][H][w * 512]); \
    gload16(gAr + (size_t)(H) * 131072 + 65536 + (KT) * 128, &Asm[(KT) & 1][H][4096 + w * 512]); \
  } while (0)
#define STAGE_B(H, KT) do { \
    gload16(gBr + (size_t)(H) * 131072 + (KT) * 128,         &Bsm[(KT) & 1][H][w * 512]); \
    gload16(gBr + (size_t)(H) * 131072 + 65536 + (KT) * 128, &Bsm[(KT) & 1][H][4096 + w * 512]); \
  } while (0)

  bf16x8 aF[4][2], bF0[2][2], bF1[2][2];

#define LOAD_A(KT, MH) do { \
    const ushort* AH = &Asm[(KT) & 1][wr][0]; \
    _Pragma("unroll") \
    for (int mi = 0; mi < 4; mi++) { \
      int ro = (((MH) * 4 + mi) * 16 + fr) * 64; \
      aF[mi][0] = *(const bf16x8*)(AH + ro + sw0); \
      aF[mi][1] = *(const bf16x8*)(AH + ro + sw1); \
    } } while (0)
#define LOAD_B(KT, NH, DST) do { \
    const ushort* BH = &Bsm[(KT) & 1][wc >> 1][0]; \
    _Pragma("unroll") \
    for (int ni = 0; ni < 2; ni++) { \
      int ro = ((wc & 1) * 64 + ((NH) * 2 + ni) * 16 + fr) * 64; \
      DST[ni][0] = *(const bf16x8*)(BH + ro + sw0); \
      DST[ni][1] = *(const bf16x8*)(BH + ro + sw1); \
    } } while (0)
#define MFMA_Q(MH, NH, BSRC) do { \
    __builtin_amdgcn_s_setprio(1); \
    _Pragma("unroll") \
    for (int ks = 0; ks < 2; ks++) \
      _Pragma("unroll") \
      for (int mi = 0; mi < 4; mi++) \
        _Pragma("unroll") \
        for (int ni = 0; ni < 2; ni++) \
          acc[(MH) * 4 + mi][(NH) * 2 + ni] = __builtin_amdgcn_mfma_f32_16x16x32_bf16( \
              aF[mi][ks], BSRC[ni][ks], acc[(MH) * 4 + mi][(NH) * 2 + ni], 0, 0, 0); \
    __builtin_amdgcn_s_setprio(0); \
  } while (0)
#define BAR() __builtin_amdgcn_s_barrier()
#define DRAIN() do { asm volatile("s_waitcnt vmcnt(0)" ::: "memory"); __builtin_amdgcn_s_barrier(); } while (0)

  // prologue: stage all 4 halves of kt0 into dbuf0
  STAGE_A(0, 0); STAGE_A(1, 0); STAGE_B(0, 0); STAGE_B(1, 0);
  DRAIN();

  #pragma unroll
  for (int it = 0; it < 4; it++) {
    const int ka = 2 * it, kb = 2 * it + 1;
    // P0: quadrant (0,0) of ka; stage A-h0 of kb
    LOAD_A(ka, 0); LOAD_B(ka, 0, bF0);
    STAGE_A(0, kb);
    BAR(); MFMA_Q(0, 0, bF0); BAR();
    // P1: (0,1); stage A-h1 of kb
    LOAD_B(ka, 1, bF1);
    STAGE_A(1, kb);
    BAR(); MFMA_Q(0, 1, bF1); BAR();
    // P2: (1,0); stage B-h0 of kb
    LOAD_A(ka, 1);
    STAGE_B(0, kb);
    BAR(); MFMA_Q(1, 0, bF0); BAR();
    // P3: (1,1); stage B-h1 of kb; drain (kb complete for all waves)
    STAGE_B(1, kb);
    BAR(); MFMA_Q(1, 1, bF1);
    DRAIN();
    // P4: (0,0) of kb; stage A-h0 of ka+2
    LOAD_A(kb, 0); LOAD_B(kb, 0, bF0);
    if (it < 3) STAGE_A(0, ka + 2);
    BAR(); MFMA_Q(0, 0, bF0); BAR();
    // P5
    LOAD_B(kb, 1, bF1);
    if (it < 3) STAGE_A(1, ka + 2);
    BAR(); MFMA_Q(0, 1, bF1); BAR();
    // P6
    LOAD_A(kb, 1);
    if (it < 3) STAGE_B(0, ka + 2);
    BAR(); MFMA_Q(1, 0, bF0); BAR();
    // P7: drain (ka+2 complete for next iteration's P0)
    if (it < 3) STAGE_B(1, ka + 2);
    BAR(); MFMA_Q(1, 1, bF1);
    DRAIN();
  }
#undef STAGE_A
#undef STAGE_B
#undef LOAD_A
#undef LOAD_B
#undef MFMA_Q
#undef BAR
#undef DRAIN

  // ---- reuse LDS after K-loop ----
  __syncthreads();
  float* rpd = (float*)&Asm[0][0][0];   // [8 waves][128 rows] x 3 vals (12 KB)
  float* rpp = rpd + 1024;
  float* rpm = rpp + 1024;
  float* cps = (float*)&Bsm[0][0][0];   // [8 waves][4 n][16 cl][3] (6 KB)
  int* ridL = (int*)&Bsm[1][0][0];
  int* cidL = ridL + 256;
  if (t < 256) ridL[t] = ids[brow + t];
  else cidL[t - 256] = ids[bcol + (t - 256)];
  __syncthreads();

  float* ps = part + (size_t)tbid * SLOT;   // [side][3 vals][256]

  // ---- epilogue: per-element masks; DPP row-reduce (VALU pipe) ----
  int cl = fr;
  int cgrp = fg;
  int cidv[4];
  #pragma unroll
  for (int n = 0; n < 4; n++) cidv[n] = cidL[wc * 64 + n * 16 + cl];
  float cd[4], cp[4], cm[4];
  #pragma unroll
  for (int n = 0; n < 4; n++) { cd[n] = 0.f; cp[n] = 0.f; cm[n] = 0.f; }

  #pragma unroll
  for (int m = 0; m < 8; m++) {
    #pragma unroll
    for (int r = 0; r < 4; r++) {
      int row_l = wr * 128 + m * 16 + cgrp * 4 + r;
      int i = brow + row_l;
      int idi = ridL[row_l];
      float dsum = 0.f, psum = 0.f, msum = 0.f;
      #pragma unroll
      for (int n = 0; n < 4; n++) {
        int col_l = wc * 64 + n * 16 + cl;
        int j = bcol + col_l;
        float sim = acc[m][n][r] * INV_T;
        bool live = (!diag) || (i != j);
        if (live) {
          float e = __expf(sim);
          float hinge = fmaxf(sim + MARGIN_V, 0.f);
          bool same = (idi == cidv[n]);
          float psv = same ? sim : 0.f;
          float msv = same ? 0.f : hinge;
          dsum += e; psum += psv; msum += msv;
          if (!diag) { cd[n] += e; cp[n] += psv; cm[n] += msv; }
        }
      }
      dsum = dpp_sum16(dsum);
      psum = dpp_sum16(psum);
      msum = dpp_sum16(msum);
      if (cl == 15) {
        int o = w * 128 + (row_l & 127);
        rpd[o] = dsum; rpp[o] = psum; rpm[o] = msum;
      }
    }
  }

  if (!diag) {
    #pragma unroll
    for (int n = 0; n < 4; n++) {
      float d = cd[n], p = cp[n], mm = cm[n];
      d += __shfl_xor(d, 16); d += __shfl_xor(d, 32);
      p += __shfl_xor(p, 16); p += __shfl_xor(p, 32);
      mm += __shfl_xor(mm, 16); mm += __shfl_xor(mm, 32);
      if (l < 16) {
        int o = ((w * 4 + n) * 16 + cl) * 3;
        cps[o] = d; cps[o + 1] = p; cps[o + 2] = mm;
      }
    }
  }
  __syncthreads();

  // row side: sum the 4 wc-wave slices, coalesced store
  if (t < 256) {
    int b0 = (t >> 7) * 512 + (t & 127);
    float d = rpd[b0] + rpd[b0 + 128] + rpd[b0 + 256] + rpd[b0 + 384];
    float p = rpp[b0] + rpp[b0 + 128] + rpp[b0 + 256] + rpp[b0 + 384];
    float mm = rpm[b0] + rpm[b0 + 128] + rpm[b0 + 256] + rpm[b0 + 384];
    ps[t] = d; ps[256 + t] = p; ps[512 + t] = mm;
  }
  // col side: combine wr=0/wr=1 wave pairs, store
  if (!diag && wr == 0 && l < 16) {
    #pragma unroll
    for (int n = 0; n < 4; n++) {
      int o0 = ((w * 4 + n) * 16 + cl) * 3;
      int o1 = (((w + 4) * 4 + n) * 16 + cl) * 3;
      int col_l = wc * 64 + n * 16 + cl;
      ps[768 + col_l] = cps[o0] + cps[o1];
      ps[768 + 256 + col_l] = cps[o0 + 1] + cps[o1 + 1];
      ps[768 + 512 + col_l] = cps[o0 + 2] + cps[o1 + 2];
    }
  }
}

// ---- Kernel 3: reduce partials + per-row loss + per-block partial sum ----
__global__ __launch_bounds__(256) void k_reduce(
    const float* __restrict__ part, const int* __restrict__ mids,
    float* __restrict__ blockout) {
  __shared__ int hist[256];
  __shared__ float reds[256];
  __shared__ int redc[256];
  int t = threadIdx.x;
  hist[t] = 0;
  __syncthreads();
  for (int i = t; i < M_ROWS; i += 256) atomicAdd(&hist[mids[i]], 1);
  __syncthreads();

  int p = blockIdx.x;                       // panel 0..27
  int i = p * 256 + t;                      // row 0..7167
  float d = 0.f, pp = 0.f, mm = 0.f;
  int base = p * TILES2 - p * (p - 1) / 2;  // tbid(p, p)
  for (int yy = p; yy < TILES2; yy++) {
    const float* s = part + (size_t)(base + yy - p) * SLOT;
    d += s[t]; pp += s[256 + t]; mm += s[512 + t];
  }
  for (int xx = 0; xx < p; xx++) {
    int b = xx * TILES2 - xx * (xx - 1) / 2 + (p - xx);
    const float* s = part + (size_t)b * SLOT + 768;
    d += s[t]; pp += s[256 + t]; mm += s[512 + t];
  }

  int vmid; bool sh = false;
  if (i < TEXT_OFF) vmid = mids[i];
  else if (i < SHUF_OFF) vmid = mids[(i - TEXT_OFF) / 3];
  else { vmid = mids[(i - SHUF_OFF) / 3]; sh = true; }
  int c = hist[vmid];
  int npos = sh ? (3 * c - 1) : (4 * c - 1);
  int nneg = N_TOT - 1 - npos;
  float val = 0.f; int cnt = 0;
  if (npos > 0 && nneg > 0) {
    val = logf(d) - pp / (float)(npos > 1 ? npos : 1) + mm / (float)(nneg > 1 ? nneg : 1);
    cnt = 1;
  }
  reds[t] = val; redc[t] = cnt;
  __syncthreads();
  for (int s2 = 128; s2 > 0; s2 >>= 1) {
    if (t < s2) { reds[t] += reds[t + s2]; redc[t] += redc[t + s2]; }
    __syncthreads();
  }
  if (t == 0) { blockout[p * 2] = reds[0]; blockout[p * 2 + 1] = (float)redc[0]; }
}

// ---------------- Kernel 4: final scalar ----------------
__global__ __launch_bounds__(64) void k_final(
    const float* __restrict__ blockout, float* __restrict__ out) {
  int t = threadIdx.x;
  float s = 0.f, c = 0.f;
  if (t < TILES2) { s = blockout[t * 2]; c = blockout[t * 2 + 1]; }
  #pragma unroll
  for (int m = 32; m > 0; m >>= 1) { s += __shfl_down(s, m); c += __shfl_down(c, m); }
  if (t == 0) out[0] = (c > 0.f) ? s / c : 0.f;
}

// ---------------- Launch ----------------
extern "C" void kernel_launch(void* const* d_in, const int* in_sizes, int n_in,
                              void* d_out, int out_size, void* d_ws, size_t ws_size,
                              hipStream_t stream) {
  const float* motion = (const float*)d_in[0];
  const float* text   = (const float*)d_in[1];
  const float* shuf   = (const float*)d_in[2];
  const int*   mids   = (const int*)d_in[3];

  char* ws = (char*)d_ws;
  ushort* emb = (ushort*)ws;                                  // 7,340,032 B
  int* ids    = (int*)(ws + 7340032);                         // 28,672 B
  float* blockout = (float*)(ws + 7368704);                   // 28*2 floats
  float* part = (float*)(ws + 7454720);                       // 406*1536*4 B

  k_normalize<<<N_TOT / 4, 256, 0, stream>>>(motion, text, shuf, mids, emb, ids);
  k_gemm_loss<<<NBLK2, 512, 0, stream>>>(emb, ids, part);
  k_reduce<<<TILES2, 256, 0, stream>>>(part, mids, blockout);
  k_final<<<1, 64, 0, stream>>>(blockout, (float*)d_out);
}

// Round 14
// 72.582 us; speedup vs baseline: 1.3470x; 1.0373x over previous
//
#include <hip/hip_runtime.h>

#define M_ROWS 1024
#define DIM 512
#define NB 512               // row bytes = DIM fp8
#define N_TOT 7168           // M + 2*M*C
#define TEXT_OFF 1024
#define SHUF_OFF 4096
#define INV_T (1.0f/0.07f)
#define MARGIN_V 0.2f
#define TILES2 28            // N_TOT / 256
#define NBLK2 406            // 28*29/2 upper-triangular 256^2 tiles
#define SLOT 1536            // floats per slot: [2 sides][3 vals][256 rows]

typedef __attribute__((ext_vector_type(4))) float f32x4;

typedef const __attribute__((address_space(1))) unsigned int gas_uint;
typedef __attribute__((address_space(3))) unsigned int las_uint;

__device__ __forceinline__ void gload16(const void* g, void* l) {
  __builtin_amdgcn_global_load_lds((gas_uint*)g, (las_uint*)l, 16, 0, 0);
}

// DPP 16-lane row sum on the VALU pipe; total lands in lane 15 of each row.
__device__ __forceinline__ float dpp_sum16(float x) {
  float s = x;
  s += __int_as_float(__builtin_amdgcn_update_dpp(0, __float_as_int(s), 0x111, 0xF, 0xF, true));
  s += __int_as_float(__builtin_amdgcn_update_dpp(0, __float_as_int(s), 0x112, 0xF, 0xF, true));
  s += __int_as_float(__builtin_amdgcn_update_dpp(0, __float_as_int(s), 0x114, 0xF, 0xF, true));
  s += __int_as_float(__builtin_amdgcn_update_dpp(0, __float_as_int(s), 0x118, 0xF, 0xF, true));
  return s;
}

// ------- Kernel 1: normalize + cast fp8 e4m3 + build ids -------
__global__ __launch_bounds__(256) void k_normalize(
    const float* __restrict__ motion, const float* __restrict__ text,
    const float* __restrict__ shuf, const int* __restrict__ mids,
    unsigned char* __restrict__ emb, int* __restrict__ ids) {
  int wave = threadIdx.x >> 6;
  int lane = threadIdx.x & 63;
  int row = blockIdx.x * 4 + wave;
  if (row >= N_TOT) return;
  const float* src;
  int id;
  if (row < TEXT_OFF) { src = motion + (size_t)row * DIM; id = mids[row]; }
  else if (row < SHUF_OFF) { int r = row - TEXT_OFF; src = text + (size_t)r * DIM; id = mids[r / 3]; }
  else { int r = row - SHUF_OFF; src = shuf + (size_t)r * DIM; id = mids[r / 3] + 100000; }

  float4 a = ((const float4*)src)[lane * 2];
  float4 b = ((const float4*)src)[lane * 2 + 1];
  float v0 = a.x + 1e-8f, v1 = a.y + 1e-8f, v2 = a.z + 1e-8f, v3 = a.w + 1e-8f;
  float v4 = b.x + 1e-8f, v5 = b.y + 1e-8f, v6 = b.z + 1e-8f, v7 = b.w + 1e-8f;
  float ss = v0*v0 + v1*v1 + v2*v2 + v3*v3 + v4*v4 + v5*v5 + v6*v6 + v7*v7;
  #pragma unroll
  for (int m = 1; m < 64; m <<= 1) ss += __shfl_xor(ss, m);
  float inv = 1.0f / fmaxf(sqrtf(ss), 1e-12f);

  // pack 8 normalized values to fp8 e4m3 (OCP) via HW converts
  int w0 = __builtin_amdgcn_cvt_pk_fp8_f32(v0 * inv, v1 * inv, 0, false);
  w0     = __builtin_amdgcn_cvt_pk_fp8_f32(v2 * inv, v3 * inv, w0, true);
  int w1 = __builtin_amdgcn_cvt_pk_fp8_f32(v4 * inv, v5 * inv, 0, false);
  w1     = __builtin_amdgcn_cvt_pk_fp8_f32(v6 * inv, v7 * inv, w1, true);
  uint2 pk; pk.x = (unsigned)w0; pk.y = (unsigned)w1;
  *((uint2*)(emb + (size_t)row * NB + lane * 8)) = pk;
  if (lane == 0) ids[row] = id;
}

// -------- Kernel 2: symmetric fused A*A^T, fp8, 256^2 tiles, 8 waves --------
// R10 structure, fp8 operands: K=64 per stage-step (same 64B/row staging
// geometry), 8 steps (half the barriers), triple-buffered counted-vmcnt
// pipeline, 16B-group XOR swizzle (store side) + b64 swizzled reads
// (~2-way, free). DPP epilogue; slot partials (no global atomics).
__global__ __launch_bounds__(512, 2) void k_gemm_loss(
    const unsigned char* __restrict__ emb, const int* __restrict__ ids,
    float* __restrict__ part) {
  __shared__ unsigned char Asm[3][16384];   // [buf][256 rows x 64 fp8] = 16 KB
  __shared__ unsigned char Bsm[3][16384];   // total static LDS = 96 KB

  // bijective XCD-chunked swizzle: nwg=406, q=50, r=6
  int orig = blockIdx.x;
  int xcd = orig & 7;
  int idx = orig >> 3;
  int bid = (xcd < 6 ? xcd * 51 : 306 + (xcd - 6) * 50) + idx;

  // triangular tile decode: bid -> (x, y), x <= y
  int x = 0;
  while (bid >= TILES2 - x) { bid -= TILES2 - x; x++; }
  int y = x + bid;
  bool diag = (x == y);
  int brow = x * 256, bcol = y * 256;
  int tbid = x * TILES2 - x * (x - 1) / 2 + (y - x);   // linear triangular id

  int t = threadIdx.x;
  int l = t & 63;
  int w = t >> 6;            // wave 0..7
  int wr = w >> 2;           // 0..1 -> 128 output rows
  int wc = w & 3;            // 0..3 -> 64 output cols
  int fr = l & 15;
  int fg = l >> 4;           // 0..3

  // staging: lane l stages row (w*16 + l>>2) of each 128-row chunk; source
  // 16B-group pre-swizzled: g_src = (l&3) ^ ((l>>3)&3)  [= (srow>>1)&3]
  int srow = w * 16 + (l >> 2);
  int scol = ((l & 3) ^ ((l >> 3) & 3)) * 16;
  const char* gA = (const char*)emb + (size_t)(brow + srow) * NB + scol;
  const char* gB = (const char*)emb + (size_t)(bcol + srow) * NB + scol;
  int ldso = w * 1024;

  f32x4 acc[8][4];
  #pragma unroll
  for (int m = 0; m < 8; m++)
    #pragma unroll
    for (int n = 0; n < 4; n++)
      acc[m][n] = (f32x4){0.f, 0.f, 0.f, 0.f};

  // read-side swizzle: logical 8B-group g8 = kh*4+fg lives at byte
  // ((g8>>1) ^ ((fr>>1)&3))*16 + (g8&1)*8 within the row
  int rsw = (fr >> 1) & 3;

#define STAGE(T) do { \
    const int _b = (T) % 3; const int _kb = (T) * 64; \
    gload16(gA + _kb,         &Asm[_b][ldso]); \
    gload16(gA + 65536 + _kb, &Asm[_b][8192 + ldso]); \
    gload16(gB + _kb,         &Bsm[_b][ldso]); \
    gload16(gB + 65536 + _kb, &Bsm[_b][8192 + ldso]); \
  } while (0)

  // prologue: tiles 0 and 1 in flight; wait tile 0 only
  STAGE(0);
  STAGE(1);
  asm volatile("s_waitcnt vmcnt(4)" ::: "memory");
  __builtin_amdgcn_s_barrier();

  #pragma unroll
  for (int tt = 0; tt < 8; tt++) {
    if (tt + 2 < 8) STAGE(tt + 2);   // disjoint buffer: no read conflict
    const int _b = tt % 3;
    long aF[8][2], bF[4][2];
    #pragma unroll
    for (int kh = 0; kh < 2; kh++) {
      int g0 = kh * 4 + fg;
      int goff = (((g0 >> 1) ^ rsw) * 16) + (g0 & 1) * 8;
      #pragma unroll
      for (int m = 0; m < 8; m++)
        aF[m][kh] = *(const long*)(&Asm[_b][(wr * 128 + m * 16 + fr) * 64 + goff]);
      #pragma unroll
      for (int n = 0; n < 4; n++)
        bF[n][kh] = *(const long*)(&Bsm[_b][(wc * 64 + n * 16 + fr) * 64 + goff]);
    }
    __builtin_amdgcn_s_setprio(1);
    #pragma unroll
    for (int kh = 0; kh < 2; kh++)
      #pragma unroll
      for (int m = 0; m < 8; m++)
        #pragma unroll
        for (int n = 0; n < 4; n++)
          acc[m][n] = __builtin_amdgcn_mfma_f32_16x16x32_fp8_fp8(aF[m][kh], bF[n][kh], acc[m][n], 0, 0, 0);
    __builtin_amdgcn_s_setprio(0);
    if (tt < 6) {
      asm volatile("s_waitcnt vmcnt(4)" ::: "memory");   // retire tile tt+1
      __builtin_amdgcn_s_barrier();
    } else if (tt == 6) {
      asm volatile("s_waitcnt vmcnt(0)" ::: "memory");
      __builtin_amdgcn_s_barrier();
    }
  }
#undef STAGE

  // ---- reuse LDS after K-loop ----
  // Last step (tt=7) reads buf 1 only. Safe now (post tt6-barrier): buf 0
  // (rpd/rpp/rpm), Bsm[0] (cps), buf 2 (ids). rpd written only at epilogue.
  float* rpd = (float*)&Asm[0][0];      // [8 waves][128 rows] x 3 vals (12 KB)
  float* rpp = rpd + 1024;
  float* rpm = rpp + 1024;
  float* cps = (float*)&Bsm[0][0];      // [8 waves][4 n][16 cl][3] (6 KB)
  int* ridL = (int*)&Asm[2][0];
  int* cidL = ridL + 256;
  if (t < 256) ridL[t] = ids[brow + t];
  else cidL[t - 256] = ids[bcol + (t - 256)];
  __syncthreads();

  float* ps = part + (size_t)tbid * SLOT;   // [side][3 vals][256]

  // ---- epilogue: per-element masks; DPP row-reduce (VALU pipe) ----
  int cl = fr;
  int cgrp = fg;
  int cidv[4];
  #pragma unroll
  for (int n = 0; n < 4; n++) cidv[n] = cidL[wc * 64 + n * 16 + cl];
  float cd[4], cp[4], cm[4];
  #pragma unroll
  for (int n = 0; n < 4; n++) { cd[n] = 0.f; cp[n] = 0.f; cm[n] = 0.f; }

  #pragma unroll
  for (int m = 0; m < 8; m++) {
    #pragma unroll
    for (int r = 0; r < 4; r++) {
      int row_l = wr * 128 + m * 16 + cgrp * 4 + r;
      int i = brow + row_l;
      int idi = ridL[row_l];
      float dsum = 0.f, psum = 0.f, msum = 0.f;
      #pragma unroll
      for (int n = 0; n < 4; n++) {
        int col_l = wc * 64 + n * 16 + cl;
        int j = bcol + col_l;
        float sim = acc[m][n][r] * INV_T;
        bool live = (!diag) || (i != j);
        if (live) {
          float e = __expf(sim);
          float hinge = fmaxf(sim + MARGIN_V, 0.f);
          bool same = (idi == cidv[n]);
          float psv = same ? sim : 0.f;
          float msv = same ? 0.f : hinge;
          dsum += e; psum += psv; msum += msv;
          if (!diag) { cd[n] += e; cp[n] += psv; cm[n] += msv; }
        }
      }
      dsum = dpp_sum16(dsum);
      psum = dpp_sum16(psum);
      msum = dpp_sum16(msum);
      if (cl == 15) {
        int o = w * 128 + (row_l & 127);
        rpd[o] = dsum; rpp[o] = psum; rpm[o] = msum;
      }
    }
  }

  if (!diag) {
    #pragma unroll
    for (int n = 0; n < 4; n++) {
      float d = cd[n], p = cp[n], mm = cm[n];
      d += __shfl_xor(d, 16); d += __shfl_xor(d, 32);
      p += __shfl_xor(p, 16); p += __shfl_xor(p, 32);
      mm += __shfl_xor(mm, 16); mm += __shfl_xor(mm, 32);
      if (l < 16) {
        int o = ((w * 4 + n) * 16 + cl) * 3;
        cps[o] = d; cps[o + 1] = p; cps[o + 2] = mm;
      }
    }
  }
  __syncthreads();

  // row side: sum the 4 wc-wave slices, coalesced store
  if (t < 256) {
    int b0 = (t >> 7) * 512 + (t & 127);
    float d = rpd[b0] + rpd[b0 + 128] + rpd[b0 + 256] + rpd[b0 + 384];
    float p = rpp[b0] + rpp[b0 + 128] + rpp[b0 + 256] + rpp[b0 + 384];
    float mm = rpm[b0] + rpm[b0 + 128] + rpm[b0 + 256] + rpm[b0 + 384];
    ps[t] = d; ps[256 + t] = p; ps[512 + t] = mm;
  }
  // col side: combine wr=0/wr=1 wave pairs, store
  if (!diag && wr == 0 && l < 16) {
    #pragma unroll
    for (int n = 0; n < 4; n++) {
      int o0 = ((w * 4 + n) * 16 + cl) * 3;
      int o1 = (((w + 4) * 4 + n) * 16 + cl) * 3;
      int col_l = wc * 64 + n * 16 + cl;
      ps[768 + col_l] = cps[o0] + cps[o1];
      ps[768 + 256 + col_l] = cps[o0 + 1] + cps[o1 + 1];
      ps[768 + 512 + col_l] = cps[o0 + 2] + cps[o1 + 2];
    }
  }
}

// ---- Kernel 3: reduce partials + per-row loss + per-block partial sum ----
__global__ __launch_bounds__(128) void k_reduce(
    const float* __restrict__ part, const int* __restrict__ mids,
    float* __restrict__ blockout) {
  __shared__ int hist[256];
  __shared__ float reds[128];
  __shared__ int redc[128];
  int t = threadIdx.x;
  hist[t] = 0; hist[t + 128] = 0;
  __syncthreads();
  for (int i = t; i < M_ROWS; i += 128) atomicAdd(&hist[mids[i]], 1);
  __syncthreads();

  int i = blockIdx.x * 128 + t;             // row 0..7167 (56 blocks x 128)
  int p = blockIdx.x >> 1;                  // panel 0..27 (block-uniform)
  int v = i & 255;
  float d = 0.f, pp = 0.f, mm = 0.f;
  int base = p * TILES2 - p * (p - 1) / 2;  // tbid(p, p)
  for (int yy = p; yy < TILES2; yy++) {     // row-side from tiles (p, yy)
    const float* s = part + (size_t)(base + yy - p) * SLOT;
    d += s[v]; pp += s[256 + v]; mm += s[512 + v];
  }
  for (int xx = 0; xx < p; xx++) {          // col-side from tiles (xx, p)
    int b = xx * TILES2 - xx * (xx - 1) / 2 + (p - xx);
    const float* s = part + (size_t)b * SLOT + 768;
    d += s[v]; pp += s[256 + v]; mm += s[512 + v];
  }

  int vmid; bool sh = false;
  if (i < TEXT_OFF) vmid = mids[i];
  else if (i < SHUF_OFF) vmid = mids[(i - TEXT_OFF) / 3];
  else { vmid = mids[(i - SHUF_OFF) / 3]; sh = true; }
  int c = hist[vmid];
  int npos = sh ? (3 * c - 1) : (4 * c - 1);
  int nneg = N_TOT - 1 - npos;
  float val = 0.f; int cnt = 0;
  if (npos > 0 && nneg > 0) {
    val = logf(d) - pp / (float)(npos > 1 ? npos : 1) + mm / (float)(nneg > 1 ? nneg : 1);
    cnt = 1;
  }
  reds[t] = val; redc[t] = cnt;
  __syncthreads();
  for (int s2 = 64; s2 > 0; s2 >>= 1) {
    if (t < s2) { reds[t] += reds[t + s2]; redc[t] += redc[t + s2]; }
    __syncthreads();
  }
  if (t == 0) { blockout[blockIdx.x * 2] = reds[0]; blockout[blockIdx.x * 2 + 1] = (float)redc[0]; }
}

// ---------------- Kernel 4: final scalar ----------------
__global__ __launch_bounds__(64) void k_final(
    const float* __restrict__ blockout, float* __restrict__ out) {
  int t = threadIdx.x;
  float s = 0.f, c = 0.f;
  if (t < 56) { s = blockout[t * 2]; c = blockout[t * 2 + 1]; }
  #pragma unroll
  for (int m = 32; m > 0; m >>= 1) { s += __shfl_down(s, m); c += __shfl_down(c, m); }
  if (t == 0) out[0] = (c > 0.f) ? s / c : 0.f;
}

// ---------------- Launch ----------------
extern "C" void kernel_launch(void* const* d_in, const int* in_sizes, int n_in,
                              void* d_out, int out_size, void* d_ws, size_t ws_size,
                              hipStream_t stream) {
  const float* motion = (const float*)d_in[0];
  const float* text   = (const float*)d_in[1];
  const float* shuf   = (const float*)d_in[2];
  const int*   mids   = (const int*)d_in[3];

  char* ws = (char*)d_ws;
  unsigned char* emb = (unsigned char*)ws;                    // 3,670,016 B
  int* ids    = (int*)(ws + 3670016);                         // 28,672 B
  float* blockout = (float*)(ws + 3698688);                   // 56*2 floats
  float* part = (float*)(ws + 3702784);                       // 406*1536*4 = 2,494,464 B

  k_normalize<<<N_TOT / 4, 256, 0, stream>>>(motion, text, shuf, mids, emb, ids);
  k_gemm_loss<<<NBLK2, 512, 0, stream>>>(emb, ids, part);
  k_reduce<<<56, 128, 0, stream>>>(part, mids, blockout);
  k_final<<<1, 64, 0, stream>>>(blockout, (float*)d_out);
}

// Round 15
// 65.910 us; speedup vs baseline: 1.4833x; 1.1012x over previous
//
#include <hip/hip_runtime.h>

#define M_ROWS 1024
#define DIM 512
#define NB 512               // row bytes = DIM fp8
#define N_TOT 7168           // M + 2*M*C
#define TEXT_OFF 1024
#define SHUF_OFF 4096
#define INV_T (1.0f/0.07f)
#define MARGIN_V 0.2f
#define TILES2 28            // N_TOT / 256
#define NBLK2 406            // 28*29/2 upper-triangular 256^2 tiles
#define SLOT 1536            // floats per slot: [2 sides][3 vals][256 rows]

typedef __attribute__((ext_vector_type(4))) float f32x4;

typedef const __attribute__((address_space(1))) unsigned int gas_uint;
typedef __attribute__((address_space(3))) unsigned int las_uint;

__device__ __forceinline__ void gload16(const void* g, void* l) {
  __builtin_amdgcn_global_load_lds((gas_uint*)g, (las_uint*)l, 16, 0, 0);
}

// DPP 16-lane row sum on the VALU pipe; total lands in lane 15 of each row.
__device__ __forceinline__ float dpp_sum16(float x) {
  float s = x;
  s += __int_as_float(__builtin_amdgcn_update_dpp(0, __float_as_int(s), 0x111, 0xF, 0xF, true));
  s += __int_as_float(__builtin_amdgcn_update_dpp(0, __float_as_int(s), 0x112, 0xF, 0xF, true));
  s += __int_as_float(__builtin_amdgcn_update_dpp(0, __float_as_int(s), 0x114, 0xF, 0xF, true));
  s += __int_as_float(__builtin_amdgcn_update_dpp(0, __float_as_int(s), 0x118, 0xF, 0xF, true));
  return s;
}

// ------- Kernel 1: normalize + cast fp8 e4m3 + build ids -------
__global__ __launch_bounds__(256) void k_normalize(
    const float* __restrict__ motion, const float* __restrict__ text,
    const float* __restrict__ shuf, const int* __restrict__ mids,
    unsigned char* __restrict__ emb, int* __restrict__ ids) {
  int wave = threadIdx.x >> 6;
  int lane = threadIdx.x & 63;
  int row = blockIdx.x * 4 + wave;
  if (row >= N_TOT) return;
  const float* src;
  int id;
  if (row < TEXT_OFF) { src = motion + (size_t)row * DIM; id = mids[row]; }
  else if (row < SHUF_OFF) { int r = row - TEXT_OFF; src = text + (size_t)r * DIM; id = mids[r / 3]; }
  else { int r = row - SHUF_OFF; src = shuf + (size_t)r * DIM; id = mids[r / 3] + 100000; }

  float4 a = ((const float4*)src)[lane * 2];
  float4 b = ((const float4*)src)[lane * 2 + 1];
  float v0 = a.x + 1e-8f, v1 = a.y + 1e-8f, v2 = a.z + 1e-8f, v3 = a.w + 1e-8f;
  float v4 = b.x + 1e-8f, v5 = b.y + 1e-8f, v6 = b.z + 1e-8f, v7 = b.w + 1e-8f;
  float ss = v0*v0 + v1*v1 + v2*v2 + v3*v3 + v4*v4 + v5*v5 + v6*v6 + v7*v7;
  #pragma unroll
  for (int m = 1; m < 64; m <<= 1) ss += __shfl_xor(ss, m);
  float inv = 1.0f / fmaxf(sqrtf(ss), 1e-12f);

  // pack 8 normalized values to fp8 e4m3 (OCP) via HW converts
  int w0 = __builtin_amdgcn_cvt_pk_fp8_f32(v0 * inv, v1 * inv, 0, false);
  w0     = __builtin_amdgcn_cvt_pk_fp8_f32(v2 * inv, v3 * inv, w0, true);
  int w1 = __builtin_amdgcn_cvt_pk_fp8_f32(v4 * inv, v5 * inv, 0, false);
  w1     = __builtin_amdgcn_cvt_pk_fp8_f32(v6 * inv, v7 * inv, w1, true);
  uint2 pk; pk.x = (unsigned)w0; pk.y = (unsigned)w1;
  *((uint2*)(emb + (size_t)row * NB + lane * 8)) = pk;
  if (lane == 0) ids[row] = id;
}

// -------- Kernel 2: symmetric fused A*A^T, fp8, 256^2 tiles, 8 waves --------
// (R14 verbatim — fastest verified variant, at the measured structural floor)
__global__ __launch_bounds__(512, 2) void k_gemm_loss(
    const unsigned char* __restrict__ emb, const int* __restrict__ ids,
    float* __restrict__ part) {
  __shared__ unsigned char Asm[3][16384];   // [buf][256 rows x 64 fp8] = 16 KB
  __shared__ unsigned char Bsm[3][16384];   // total static LDS = 96 KB

  // bijective XCD-chunked swizzle: nwg=406, q=50, r=6
  int orig = blockIdx.x;
  int xcd = orig & 7;
  int idx = orig >> 3;
  int bid = (xcd < 6 ? xcd * 51 : 306 + (xcd - 6) * 50) + idx;

  // triangular tile decode: bid -> (x, y), x <= y
  int x = 0;
  while (bid >= TILES2 - x) { bid -= TILES2 - x; x++; }
  int y = x + bid;
  bool diag = (x == y);
  int brow = x * 256, bcol = y * 256;
  int tbid = x * TILES2 - x * (x - 1) / 2 + (y - x);   // linear triangular id

  int t = threadIdx.x;
  int l = t & 63;
  int w = t >> 6;            // wave 0..7
  int wr = w >> 2;           // 0..1 -> 128 output rows
  int wc = w & 3;            // 0..3 -> 64 output cols
  int fr = l & 15;
  int fg = l >> 4;           // 0..3

  // staging: lane l stages row (w*16 + l>>2) of each 128-row chunk; source
  // 16B-group pre-swizzled: g_src = (l&3) ^ ((l>>3)&3)  [= (srow>>1)&3]
  int srow = w * 16 + (l >> 2);
  int scol = ((l & 3) ^ ((l >> 3) & 3)) * 16;
  const char* gA = (const char*)emb + (size_t)(brow + srow) * NB + scol;
  const char* gB = (const char*)emb + (size_t)(bcol + srow) * NB + scol;
  int ldso = w * 1024;

  f32x4 acc[8][4];
  #pragma unroll
  for (int m = 0; m < 8; m++)
    #pragma unroll
    for (int n = 0; n < 4; n++)
      acc[m][n] = (f32x4){0.f, 0.f, 0.f, 0.f};

  // read-side swizzle: logical 8B-group g8 = kh*4+fg lives at byte
  // ((g8>>1) ^ ((fr>>1)&3))*16 + (g8&1)*8 within the row
  int rsw = (fr >> 1) & 3;

#define STAGE(T) do { \
    const int _b = (T) % 3; const int _kb = (T) * 64; \
    gload16(gA + _kb,         &Asm[_b][ldso]); \
    gload16(gA + 65536 + _kb, &Asm[_b][8192 + ldso]); \
    gload16(gB + _kb,         &Bsm[_b][ldso]); \
    gload16(gB + 65536 + _kb, &Bsm[_b][8192 + ldso]); \
  } while (0)

  // prologue: tiles 0 and 1 in flight; wait tile 0 only
  STAGE(0);
  STAGE(1);
  asm volatile("s_waitcnt vmcnt(4)" ::: "memory");
  __builtin_amdgcn_s_barrier();

  #pragma unroll
  for (int tt = 0; tt < 8; tt++) {
    if (tt + 2 < 8) STAGE(tt + 2);   // disjoint buffer: no read conflict
    const int _b = tt % 3;
    long aF[8][2], bF[4][2];
    #pragma unroll
    for (int kh = 0; kh < 2; kh++) {
      int g0 = kh * 4 + fg;
      int goff = (((g0 >> 1) ^ rsw) * 16) + (g0 & 1) * 8;
      #pragma unroll
      for (int m = 0; m < 8; m++)
        aF[m][kh] = *(const long*)(&Asm[_b][(wr * 128 + m * 16 + fr) * 64 + goff]);
      #pragma unroll
      for (int n = 0; n < 4; n++)
        bF[n][kh] = *(const long*)(&Bsm[_b][(wc * 64 + n * 16 + fr) * 64 + goff]);
    }
    __builtin_amdgcn_s_setprio(1);
    #pragma unroll
    for (int kh = 0; kh < 2; kh++)
      #pragma unroll
      for (int m = 0; m < 8; m++)
        #pragma unroll
        for (int n = 0; n < 4; n++)
          acc[m][n] = __builtin_amdgcn_mfma_f32_16x16x32_fp8_fp8(aF[m][kh], bF[n][kh], acc[m][n], 0, 0, 0);
    __builtin_amdgcn_s_setprio(0);
    if (tt < 6) {
      asm volatile("s_waitcnt vmcnt(4)" ::: "memory");   // retire tile tt+1
      __builtin_amdgcn_s_barrier();
    } else if (tt == 6) {
      asm volatile("s_waitcnt vmcnt(0)" ::: "memory");
      __builtin_amdgcn_s_barrier();
    }
  }
#undef STAGE

  // ---- reuse LDS after K-loop ----
  float* rpd = (float*)&Asm[0][0];      // [8 waves][128 rows] x 3 vals (12 KB)
  float* rpp = rpd + 1024;
  float* rpm = rpp + 1024;
  float* cps = (float*)&Bsm[0][0];      // [8 waves][4 n][16 cl][3] (6 KB)
  int* ridL = (int*)&Asm[2][0];
  int* cidL = ridL + 256;
  if (t < 256) ridL[t] = ids[brow + t];
  else cidL[t - 256] = ids[bcol + (t - 256)];
  __syncthreads();

  float* ps = part + (size_t)tbid * SLOT;   // [side][3 vals][256]

  // ---- epilogue: per-element masks; DPP row-reduce (VALU pipe) ----
  int cl = fr;
  int cgrp = fg;
  int cidv[4];
  #pragma unroll
  for (int n = 0; n < 4; n++) cidv[n] = cidL[wc * 64 + n * 16 + cl];
  float cd[4], cp[4], cm[4];
  #pragma unroll
  for (int n = 0; n < 4; n++) { cd[n] = 0.f; cp[n] = 0.f; cm[n] = 0.f; }

  #pragma unroll
  for (int m = 0; m < 8; m++) {
    #pragma unroll
    for (int r = 0; r < 4; r++) {
      int row_l = wr * 128 + m * 16 + cgrp * 4 + r;
      int i = brow + row_l;
      int idi = ridL[row_l];
      float dsum = 0.f, psum = 0.f, msum = 0.f;
      #pragma unroll
      for (int n = 0; n < 4; n++) {
        int col_l = wc * 64 + n * 16 + cl;
        int j = bcol + col_l;
        float sim = acc[m][n][r] * INV_T;
        bool live = (!diag) || (i != j);
        if (live) {
          float e = __expf(sim);
          float hinge = fmaxf(sim + MARGIN_V, 0.f);
          bool same = (idi == cidv[n]);
          float psv = same ? sim : 0.f;
          float msv = same ? 0.f : hinge;
          dsum += e; psum += psv; msum += msv;
          if (!diag) { cd[n] += e; cp[n] += psv; cm[n] += msv; }
        }
      }
      dsum = dpp_sum16(dsum);
      psum = dpp_sum16(psum);
      msum = dpp_sum16(msum);
      if (cl == 15) {
        int o = w * 128 + (row_l & 127);
        rpd[o] = dsum; rpp[o] = psum; rpm[o] = msum;
      }
    }
  }

  if (!diag) {
    #pragma unroll
    for (int n = 0; n < 4; n++) {
      float d = cd[n], p = cp[n], mm = cm[n];
      d += __shfl_xor(d, 16); d += __shfl_xor(d, 32);
      p += __shfl_xor(p, 16); p += __shfl_xor(p, 32);
      mm += __shfl_xor(mm, 16); mm += __shfl_xor(mm, 32);
      if (l < 16) {
        int o = ((w * 4 + n) * 16 + cl) * 3;
        cps[o] = d; cps[o + 1] = p; cps[o + 2] = mm;
      }
    }
  }
  __syncthreads();

  // row side: sum the 4 wc-wave slices, coalesced store
  if (t < 256) {
    int b0 = (t >> 7) * 512 + (t & 127);
    float d = rpd[b0] + rpd[b0 + 128] + rpd[b0 + 256] + rpd[b0 + 384];
    float p = rpp[b0] + rpp[b0 + 128] + rpp[b0 + 256] + rpp[b0 + 384];
    float mm = rpm[b0] + rpm[b0 + 128] + rpm[b0 + 256] + rpm[b0 + 384];
    ps[t] = d; ps[256 + t] = p; ps[512 + t] = mm;
  }
  // col side: combine wr=0/wr=1 wave pairs, store
  if (!diag && wr == 0 && l < 16) {
    #pragma unroll
    for (int n = 0; n < 4; n++) {
      int o0 = ((w * 4 + n) * 16 + cl) * 3;
      int o1 = (((w + 4) * 4 + n) * 16 + cl) * 3;
      int col_l = wc * 64 + n * 16 + cl;
      ps[768 + col_l] = cps[o0] + cps[o1];
      ps[768 + 256 + col_l] = cps[o0 + 1] + cps[o1 + 1];
      ps[768 + 512 + col_l] = cps[o0 + 2] + cps[o1 + 2];
    }
  }
}

// ---- Kernel 3: reduce partials + per-row loss + per-block partial sum ----
// Uniform 28-contribution loop (row i in panel p sums tile-pairs (p,c) for
// all c): fully unrolled, block-uniform scalar addressing, 84 independent
// loads -> deep MLP instead of two dynamic-bound serial loops.
__global__ __launch_bounds__(128) void k_reduce(
    const float* __restrict__ part, const int* __restrict__ mids,
    float* __restrict__ blockout) {
  __shared__ int hist[256];
  __shared__ float reds[128];
  __shared__ int redc[128];
  int t = threadIdx.x;
  hist[t] = 0; hist[t + 128] = 0;
  __syncthreads();
  for (int i = t; i < M_ROWS; i += 128) atomicAdd(&hist[mids[i]], 1);
  __syncthreads();

  int i = blockIdx.x * 128 + t;             // row 0..7167 (56 blocks x 128)
  int p = blockIdx.x >> 1;                  // panel 0..27 (block-uniform)
  int v = (blockIdx.x & 1) * 128 + t;       // row within panel (0..255)
  float d = 0.f, pp = 0.f, mm = 0.f;
  #pragma unroll
  for (int c = 0; c < TILES2; c++) {
    int lo = c < p ? c : p;
    int hi = c < p ? p : c;
    int off = c < p ? 768 : 0;              // col-side slot half when c < p
    const float* s = part + (size_t)(lo * TILES2 - lo * (lo - 1) / 2 + (hi - lo)) * SLOT + off;
    d += s[v]; pp += s[256 + v]; mm += s[512 + v];
  }

  int vmid; bool sh = false;
  if (i < TEXT_OFF) vmid = mids[i];
  else if (i < SHUF_OFF) vmid = mids[(i - TEXT_OFF) / 3];
  else { vmid = mids[(i - SHUF_OFF) / 3]; sh = true; }
  int c2 = hist[vmid];
  int npos = sh ? (3 * c2 - 1) : (4 * c2 - 1);
  int nneg = N_TOT - 1 - npos;
  float val = 0.f; int cnt = 0;
  if (npos > 0 && nneg > 0) {
    val = logf(d) - pp / (float)(npos > 1 ? npos : 1) + mm / (float)(nneg > 1 ? nneg : 1);
    cnt = 1;
  }
  reds[t] = val; redc[t] = cnt;
  __syncthreads();
  for (int s2 = 64; s2 > 0; s2 >>= 1) {
    if (t < s2) { reds[t] += reds[t + s2]; redc[t] += redc[t + s2]; }
    __syncthreads();
  }
  if (t == 0) { blockout[blockIdx.x * 2] = reds[0]; blockout[blockIdx.x * 2 + 1] = (float)redc[0]; }
}

// ---------------- Kernel 4: final scalar ----------------
__global__ __launch_bounds__(64) void k_final(
    const float* __restrict__ blockout, float* __restrict__ out) {
  int t = threadIdx.x;
  float s = 0.f, c = 0.f;
  if (t < 56) { s = blockout[t * 2]; c = blockout[t * 2 + 1]; }
  #pragma unroll
  for (int m = 32; m > 0; m >>= 1) { s += __shfl_down(s, m); c += __shfl_down(c, m); }
  if (t == 0) out[0] = (c > 0.f) ? s / c : 0.f;
}

// ---------------- Launch ----------------
extern "C" void kernel_launch(void* const* d_in, const int* in_sizes, int n_in,
                              void* d_out, int out_size, void* d_ws, size_t ws_size,
                              hipStream_t stream) {
  const float* motion = (const float*)d_in[0];
  const float* text   = (const float*)d_in[1];
  const float* shuf   = (const float*)d_in[2];
  const int*   mids   = (const int*)d_in[3];

  char* ws = (char*)d_ws;
  unsigned char* emb = (unsigned char*)ws;                    // 3,670,016 B
  int* ids    = (int*)(ws + 3670016);                         // 28,672 B
  float* blockout = (float*)(ws + 3698688);                   // 56*2 floats
  float* part = (float*)(ws + 3702784);                       // 406*1536*4 = 2,494,464 B

  k_normalize<<<N_TOT / 4, 256, 0, stream>>>(motion, text, shuf, mids, emb, ids);
  k_gemm_loss<<<NBLK2, 512, 0, stream>>>(emb, ids, part);
  k_reduce<<<56, 128, 0, stream>>>(part, mids, blockout);
  k_final<<<1, 64, 0, stream>>>(blockout, (float*)d_out);
}